// Round 1
// baseline (426.080 us; speedup 1.0000x reference)
//
#include <hip/hip_runtime.h>

namespace {
constexpr int Cc  = 64;    // channels
constexpr int Hh  = 128;
constexpr int Ww  = 128;
constexpr int Rr  = 5;
constexpr int Pp  = 8;
constexpr int CPk = Cc * Pp;   // 512 = K of GEMM1
constexpr int HWn = Hh * Ww;   // 16384
constexpr int PIX = 64;        // pixels per block (row segment)
constexpr int KC  = 64;        // K-chunk = 8 channels x 8 points
constexpr int FP  = 68;        // padded px-dim for featT
constexpr int NP  = 68;        // padded n-dim for wbuf/hbuf
}

__global__ __launch_bounds__(256, 2)
void rrf_fp32(const float* __restrict__ x,  const float* __restrict__ W1,
              const float* __restrict__ b1v, const float* __restrict__ g1v,
              const float* __restrict__ btv, const float* __restrict__ W2,
              const float* __restrict__ b2v, float* __restrict__ out)
{
    __shared__ float featT[KC][FP];   // [k_local][px]; reused as h^T [k=64][px] for GEMM2
    __shared__ float wbuf[KC][NP];    // W1 chunk [k_local][n]; reused for W2 [k][n]
    __shared__ float hbuf[PIX][NP];   // h [px][n]
    __shared__ float mu_s[PIX];
    __shared__ float rs_s[PIX];

    const int tid = threadIdx.x;
    const int bid = blockIdx.x;
    const int b    = bid >> 8;          // 256 blocks per image (16384/64)
    const int rem  = bid & 255;
    const int irow = rem >> 1;          // 2 segments per row
    const int j0   = (rem & 1) * PIX;

    const int lane = tid & 63;
    const int wv   = tid >> 6;          // wave 0..3
    const int pxg  = lane & 15;         // 16 pixel groups of 4
    const int ngr  = lane >> 4;         // 0..3
    const int px0  = pxg * 4;
    const int n0   = wv * 16 + ngr * 4; // 4 output channels per thread

    // gather mapping: within a wave, lane = px (coalesced x reads), wave -> channel pair
    const int gpx = lane;
    const int gcq = wv;

    const float fi = (float)irow;
    const float fj = (float)(j0 + gpx);

    float acc2[4][4] = {};              // persistent accumulator over r

    for (int r = 0; r < Rr; ++r) {
        // ring offsets, matching jnp.linspace(0, 2pi, 9)[:-1] in f32
        float dI[Pp], dJ[Pp];
        #pragma unroll
        for (int p = 0; p < Pp; ++p) {
            float ang = (float)p * 0.78539818525314331f;  // f32(2pi)/8
            dI[p] = (float)r * sinf(ang);
            dJ[p] = (float)r * cosf(ang);
        }

        float h[4][4] = {};

        for (int kc = 0; kc < CPk / KC; ++kc) {
            // ---- stage W1 chunk [KC][64] ----
            const float* w1p = W1 + ((size_t)r * CPk + (size_t)kc * KC) * 64;
            #pragma unroll
            for (int u = 0; u < 4; ++u) {
                int f = (tid + u * 256) * 4;                 // 4096 floats / chunk
                float4 v = *reinterpret_cast<const float4*>(w1p + f);
                *reinterpret_cast<float4*>(&wbuf[f >> 6][f & 63]) = v;
            }
            // ---- gather feat chunk: k_local = cl*8 + p, c = kc*8 + cl ----
            const int cbase = kc * 8;
            #pragma unroll
            for (int p = 0; p < Pp; ++p) {
                float yy  = fi + dI[p];
                float xx  = fj + dJ[p];
                float y0f = floorf(yy), x0f = floorf(xx);
                float wy  = yy - y0f,   wx  = xx - x0f;
                int y0 = (int)y0f, xq = (int)x0f;
                int y1 = y0 + 1,   x1 = xq + 1;
                float m00 = (y0 >= 0 && y0 < Hh && xq >= 0 && xq < Ww) ? 1.f : 0.f;
                float m01 = (y0 >= 0 && y0 < Hh && x1 >= 0 && x1 < Ww) ? 1.f : 0.f;
                float m10 = (y1 >= 0 && y1 < Hh && xq >= 0 && xq < Ww) ? 1.f : 0.f;
                float m11 = (y1 >= 0 && y1 < Hh && x1 >= 0 && x1 < Ww) ? 1.f : 0.f;
                int y0c = y0 < 0 ? 0 : (y0 > Hh - 1 ? Hh - 1 : y0);
                int y1c = y1 < 0 ? 0 : (y1 > Hh - 1 ? Hh - 1 : y1);
                int x0c = xq < 0 ? 0 : (xq > Ww - 1 ? Ww - 1 : xq);
                int x1c = x1 < 0 ? 0 : (x1 > Ww - 1 ? Ww - 1 : x1);
                float w00 = (1.f - wy) * (1.f - wx) * m00;
                float w01 = (1.f - wy) * wx * m01;
                float w10 = wy * (1.f - wx) * m10;
                float w11 = wy * wx * m11;
                int o00 = y0c * Ww + x0c, o01 = y0c * Ww + x1c;
                int o10 = y1c * Ww + x0c, o11 = y1c * Ww + x1c;
                #pragma unroll
                for (int cc = 0; cc < 2; ++cc) {
                    int cl = gcq * 2 + cc;
                    const float* xp = x + ((size_t)b * Cc + (cbase + cl)) * HWn;
                    float val = w00 * xp[o00] + w01 * xp[o01]
                              + w10 * xp[o10] + w11 * xp[o11];
                    featT[cl * 8 + p][gpx] = val;
                }
            }
            __syncthreads();
            // ---- GEMM1 partial: h[4px][4n] += featT^T @ W1chunk ----
            #pragma unroll 8
            for (int kk = 0; kk < KC; ++kk) {
                float4 av  = *reinterpret_cast<const float4*>(&featT[kk][px0]);
                float4 wv4 = *reinterpret_cast<const float4*>(&wbuf[kk][n0]);
                float aa[4] = {av.x, av.y, av.z, av.w};
                float ww[4] = {wv4.x, wv4.y, wv4.z, wv4.w};
                #pragma unroll
                for (int pi = 0; pi < 4; ++pi)
                    #pragma unroll
                    for (int qi = 0; qi < 4; ++qi)
                        h[pi][qi] = fmaf(aa[pi], ww[qi], h[pi][qi]);
            }
            __syncthreads();
        }

        // ---- h (+b1) -> hbuf ----
        #pragma unroll
        for (int pi = 0; pi < 4; ++pi) {
            #pragma unroll
            for (int qi = 0; qi < 4; ++qi)
                hbuf[px0 + pi][n0 + qi] = h[pi][qi] + b1v[r * 64 + n0 + qi];
        }
        __syncthreads();

        // ---- LayerNorm stats (two-pass, exact ref formula) ----
        if (tid < PIX) {
            float s = 0.f;
            #pragma unroll
            for (int nn = 0; nn < 64; ++nn) s += hbuf[tid][nn];
            float mu = s * (1.f / 64.f);
            float s2 = 0.f;
            #pragma unroll
            for (int nn = 0; nn < 64; ++nn) {
                float d = hbuf[tid][nn] - mu;
                s2 = fmaf(d, d, s2);
            }
            mu_s[tid] = mu;
            rs_s[tid] = rsqrtf(s2 * (1.f / 64.f) + 1e-5f);
        }
        __syncthreads();

        // ---- normalize + affine + exact GELU -> featT (transposed: [n][px]) ----
        {
            int px = tid >> 2, nb = (tid & 3) * 16;
            float mu = mu_s[px], rs = rs_s[px];
            const float* g1p = g1v + r * 64;
            const float* btp = btv + r * 64;
            #pragma unroll
            for (int u = 0; u < 16; ++u) {
                int nn = nb + u;
                float v = hbuf[px][nn];
                v = (v - mu) * rs * g1p[nn] + btp[nn];
                v = 0.5f * v * (1.f + erff(v * 0.70710678118654752f));
                featT[nn][px] = v;
            }
        }
        // ---- stage W2 into wbuf ----
        {
            const float* w2p = W2 + (size_t)r * 64 * 64;
            #pragma unroll
            for (int u = 0; u < 4; ++u) {
                int f = (tid + u * 256) * 4;
                float4 v = *reinterpret_cast<const float4*>(w2p + f);
                *reinterpret_cast<float4*>(&wbuf[f >> 6][f & 63]) = v;
            }
        }
        __syncthreads();

        // ---- GEMM2: acc2 += gelu(h)^ @ W2 ----
        #pragma unroll 8
        for (int kk = 0; kk < 64; ++kk) {
            float4 av  = *reinterpret_cast<const float4*>(&featT[kk][px0]);
            float4 wv4 = *reinterpret_cast<const float4*>(&wbuf[kk][n0]);
            float aa[4] = {av.x, av.y, av.z, av.w};
            float ww[4] = {wv4.x, wv4.y, wv4.z, wv4.w};
            #pragma unroll
            for (int pi = 0; pi < 4; ++pi)
                #pragma unroll
                for (int qi = 0; qi < 4; ++qi)
                    acc2[pi][qi] = fmaf(aa[pi], ww[qi], acc2[pi][qi]);
        }
        __syncthreads();
    }

    // ---- epilogue: +sum_r b2, sigmoid, gate x ----
    float sb2[4];
    #pragma unroll
    for (int qi = 0; qi < 4; ++qi) {
        float s = 0.f;
        for (int r = 0; r < Rr; ++r) s += b2v[r * 64 + n0 + qi];
        sb2[qi] = s;
    }
    #pragma unroll
    for (int pi = 0; pi < 4; ++pi) {
        int j = j0 + px0 + pi;
        #pragma unroll
        for (int qi = 0; qi < 4; ++qi) {
            int n = n0 + qi;
            size_t off = ((size_t)b * Cc + n) * HWn + (size_t)irow * Ww + j;
            float a = acc2[pi][qi] + sb2[qi];
            float wts = 1.f / (1.f + expf(-a));
            out[off] = x[off] * wts;
        }
    }
}

extern "C" void kernel_launch(void* const* d_in, const int* in_sizes, int n_in,
                              void* d_out, int out_size, void* d_ws, size_t ws_size,
                              hipStream_t stream)
{
    const float* x  = (const float*)d_in[0];
    const float* W1 = (const float*)d_in[1];
    const float* b1 = (const float*)d_in[2];
    const float* g1 = (const float*)d_in[3];
    const float* bt = (const float*)d_in[4];
    const float* W2 = (const float*)d_in[5];
    const float* b2 = (const float*)d_in[6];
    float* outp = (float*)d_out;

    rrf_fp32<<<dim3(1024), dim3(256), 0, stream>>>(x, W1, b1, g1, bt, W2, b2, outp);
}

// Round 2
// 189.358 us; speedup vs baseline: 2.2501x; 2.2501x over previous
//
#include <hip/hip_runtime.h>

namespace {
constexpr int Hh = 128, Ww = 128;
using short8 = __attribute__((ext_vector_type(8))) short;
using f32x4  = __attribute__((ext_vector_type(4))) float;

__device__ __forceinline__ unsigned short f2bf(float f) {
    union { float f; unsigned int u; } v; v.f = f;
    unsigned int u = v.u;
    unsigned int r = (u + 0x7FFFu + ((u >> 16) & 1u)) >> 16;   // RNE
    return (unsigned short)r;
}
}

// ---------------- prepack: W1/W2 fp32 -> bf16 MFMA-fragment order ----------------
__global__ void rrf_prepack(const float* __restrict__ W1, const float* __restrict__ W2,
                            unsigned short* __restrict__ w1p, unsigned short* __restrict__ w2p)
{
    int i = blockIdx.x * 256 + threadIdx.x;
    if (i < 163840) {   // (((r*4+t)*16+kc)*64+lane)*8+j
        int j    = i & 7;
        int lane = (i >> 3) & 63;
        int kc   = (i >> 9) & 15;
        int t    = (i >> 13) & 3;
        int r    = i >> 15;
        int k = kc * 32 + ((lane >> 4) << 3) + j;
        int n = t * 16 + (lane & 15);
        w1p[i] = f2bf(W1[(r * 512 + k) * 64 + n]);
    }
    if (i < 20480) {    // (((r*4+t)*2+kc2)*64+lane)*8+j
        int j    = i & 7;
        int lane = (i >> 3) & 63;
        int kc2  = (i >> 9) & 1;
        int t    = (i >> 10) & 3;
        int r    = i >> 12;
        int n = kc2 * 32 + ((lane >> 4) << 3) + j;
        int m = t * 16 + (lane & 15);
        w2p[i] = f2bf(W2[(r * 64 + n) * 64 + m]);
    }
}

// ---------------- main MFMA kernel ----------------
__global__ __launch_bounds__(256, 2)
void rrf_mfma(const float* __restrict__ x,
              const unsigned short* __restrict__ w1p, const unsigned short* __restrict__ w2p,
              const float* __restrict__ b1v, const float* __restrict__ g1v,
              const float* __restrict__ btv, const float* __restrict__ b2v,
              float* __restrict__ out)
{
    __shared__ unsigned short gbuf[4][16][72];   // per-wave gelu(h) transpose buffer

    const int tid  = threadIdx.x;
    const int w    = tid >> 6;
    const int lane = tid & 63;
    const int col  = lane & 15;          // fragment col = pixel-in-wave
    const int g    = lane >> 4;

    const int bid  = blockIdx.x;
    const int b    = bid >> 8;
    const int rem  = bid & 255;
    const int irow = rem >> 1;
    const int j0   = (rem & 1) * 64;
    const int j    = j0 + w * 16 + col;

    const float fi = (float)irow;
    const float fj = (float)j;
    const float* xb = x + ((size_t)b << 20);     // b * 64 * 16384

    f32x4 acc2[4] = {f32x4{0,0,0,0}, f32x4{0,0,0,0}, f32x4{0,0,0,0}, f32x4{0,0,0,0}};

    #pragma unroll 1
    for (int r = 0; r < 5; ++r) {
        // ---- per-point bilinear geometry (byte offsets + masked weights) ----
        int   o00[8], o01[8], o10[8], o11[8];
        float w00[8], w01[8], w10[8], w11[8];
        const float rf = (float)r;
        #pragma unroll
        for (int p = 0; p < 8; ++p) {
            float ang = (float)p * 0.78539818525314331f;   // f32(2pi)/8, matches ref linspace
            float yy = fi + rf * sinf(ang);
            float xx = fj + rf * cosf(ang);
            float y0f = floorf(yy), x0f = floorf(xx);
            float wy = yy - y0f, wx = xx - x0f;
            int y0 = (int)y0f, x0i = (int)x0f;
            int y1 = y0 + 1,   x1  = x0i + 1;
            float m00 = (y0 >= 0 && y0 < Hh && x0i >= 0 && x0i < Ww) ? 1.f : 0.f;
            float m01 = (y0 >= 0 && y0 < Hh && x1  >= 0 && x1  < Ww) ? 1.f : 0.f;
            float m10 = (y1 >= 0 && y1 < Hh && x0i >= 0 && x0i < Ww) ? 1.f : 0.f;
            float m11 = (y1 >= 0 && y1 < Hh && x1  >= 0 && x1  < Ww) ? 1.f : 0.f;
            int y0c = y0 < 0 ? 0 : (y0 > Hh - 1 ? Hh - 1 : y0);
            int y1c = y1 < 0 ? 0 : (y1 > Hh - 1 ? Hh - 1 : y1);
            int x0c = x0i < 0 ? 0 : (x0i > Ww - 1 ? Ww - 1 : x0i);
            int x1c = x1 < 0 ? 0 : (x1 > Ww - 1 ? Ww - 1 : x1);
            w00[p] = (1.f - wy) * (1.f - wx) * m00;
            w01[p] = (1.f - wy) * wx * m01;
            w10[p] = wy * (1.f - wx) * m10;
            w11[p] = wy * wx * m11;
            o00[p] = (y0c * Ww + x0c) * 4;
            o01[p] = (y0c * Ww + x1c) * 4;
            o10[p] = (y1c * Ww + x0c) * 4;
            o11[p] = (y1c * Ww + x1c) * 4;
        }

        // ---- GEMM1: h^T[n][px] = sum_k W1T[n][k] * featT[k][px], K = 512 ----
        f32x4 hv[4] = {f32x4{0,0,0,0}, f32x4{0,0,0,0}, f32x4{0,0,0,0}, f32x4{0,0,0,0}};
        const unsigned short* abase0 = w1p + ((size_t)((r * 64) * 64 + lane)) * 8;
        #pragma unroll 2
        for (int kc = 0; kc < 16; ++kc) {
            const int c = (kc << 2) + g;
            const char* xp = (const char*)(xb + ((size_t)c << 14));
            short8 bfrag;
            #pragma unroll
            for (int p = 0; p < 8; ++p) {
                float v00 = *(const float*)(xp + o00[p]);
                float v01 = *(const float*)(xp + o01[p]);
                float v10 = *(const float*)(xp + o10[p]);
                float v11 = *(const float*)(xp + o11[p]);
                float v = w00[p] * v00;
                v = fmaf(w01[p], v01, v);
                v = fmaf(w10[p], v10, v);
                v = fmaf(w11[p], v11, v);
                bfrag[p] = (short)f2bf(v);
            }
            const unsigned short* ab = abase0 + (size_t)kc * 512;   // kc stride: 64*8
            #pragma unroll
            for (int t = 0; t < 4; ++t) {
                short8 af = *(const short8*)(ab + (size_t)t * 8192); // t stride: 16*64*8
                hv[t] = __builtin_amdgcn_mfma_f32_16x16x32_bf16(af, bfrag, hv[t], 0, 0, 0);
            }
        }

        // ---- bias + LayerNorm (n split across lane bits 4-5 -> shfl reduce) ----
        const int nb = g << 2;
        float hq[4][4];
        float s = 0.f;
        #pragma unroll
        for (int t = 0; t < 4; ++t)
            #pragma unroll
            for (int q = 0; q < 4; ++q) {
                float hvq = hv[t][q] + b1v[r * 64 + t * 16 + nb + q];
                hq[t][q] = hvq;
                s += hvq;
            }
        s += __shfl_xor(s, 16);
        s += __shfl_xor(s, 32);
        const float mu = s * 0.015625f;
        float s2 = 0.f;
        #pragma unroll
        for (int t = 0; t < 4; ++t)
            #pragma unroll
            for (int q = 0; q < 4; ++q) {
                float d = hq[t][q] - mu;
                s2 = fmaf(d, d, s2);
            }
        s2 += __shfl_xor(s2, 16);
        s2 += __shfl_xor(s2, 32);
        const float rs = rsqrtf(s2 * 0.015625f + 1e-5f);

        // ---- affine + exact GELU, pack bf16 pairs into LDS (B2-fragment layout) ----
        #pragma unroll
        for (int t = 0; t < 4; ++t)
            #pragma unroll
            for (int q = 0; q < 4; ++q) {
                int n = t * 16 + nb + q;
                float v = (hq[t][q] - mu) * rs * g1v[r * 64 + n] + btv[r * 64 + n];
                hq[t][q] = 0.5f * v * (1.f + erff(v * 0.70710678118654752f));
            }
        #pragma unroll
        for (int t = 0; t < 4; ++t) {
            #pragma unroll
            for (int q2 = 0; q2 < 4; q2 += 2) {
                unsigned int u = (unsigned int)f2bf(hq[t][q2])
                               | ((unsigned int)f2bf(hq[t][q2 + 1]) << 16);
                *(unsigned int*)&gbuf[w][col][t * 16 + nb + q2] = u;
            }
        }

        // ---- GEMM2: acc2[m][px] += sum_n W2T[m][n] * gelu^T[n][px], K = 64 ----
        const unsigned short* a2base = w2p + ((size_t)((r * 8) * 64 + lane)) * 8;
        #pragma unroll
        for (int kc2 = 0; kc2 < 2; ++kc2) {
            short8 bf2 = *(const short8*)&gbuf[w][col][kc2 * 32 + g * 8];
            const unsigned short* a2 = a2base + (size_t)kc2 * 512;   // kc2 stride: 64*8
            #pragma unroll
            for (int t = 0; t < 4; ++t) {
                short8 a2f = *(const short8*)(a2 + (size_t)t * 1024); // t stride: 2*64*8
                acc2[t] = __builtin_amdgcn_mfma_f32_16x16x32_bf16(a2f, bf2, acc2[t], 0, 0, 0);
            }
        }
    }

    // ---- epilogue: + sum_r b2, sigmoid, gate x ----
    #pragma unroll
    for (int t = 0; t < 4; ++t) {
        #pragma unroll
        for (int q = 0; q < 4; ++q) {
            int m = t * 16 + (g << 2) + q;
            float sb = b2v[m] + b2v[64 + m] + b2v[128 + m] + b2v[192 + m] + b2v[256 + m];
            float a = acc2[t][q] + sb;
            float wts = 1.f / (1.f + expf(-a));
            size_t off = (((size_t)b * 64 + m) << 14) + ((size_t)irow << 7) + j;
            out[off] = x[off] * wts;
        }
    }
}

// ---------------- fallback fp32 kernel (round-1, used only if ws too small) ----------------
namespace {
constexpr int Cc  = 64;
constexpr int Rr  = 5;
constexpr int Pp  = 8;
constexpr int CPk = Cc * Pp;
constexpr int HWn = Hh * Ww;
constexpr int PIX = 64;
constexpr int KC  = 64;
constexpr int FP  = 68;
constexpr int NP  = 68;
}

__global__ __launch_bounds__(256, 2)
void rrf_fp32(const float* __restrict__ x,  const float* __restrict__ W1,
              const float* __restrict__ b1v, const float* __restrict__ g1v,
              const float* __restrict__ btv, const float* __restrict__ W2,
              const float* __restrict__ b2v, float* __restrict__ out)
{
    __shared__ float featT[KC][FP];
    __shared__ float wbuf[KC][NP];
    __shared__ float hbuf[PIX][NP];
    __shared__ float mu_s[PIX];
    __shared__ float rs_s[PIX];

    const int tid = threadIdx.x;
    const int bid = blockIdx.x;
    const int b    = bid >> 8;
    const int rem  = bid & 255;
    const int irow = rem >> 1;
    const int j0   = (rem & 1) * PIX;

    const int lane = tid & 63;
    const int wv   = tid >> 6;
    const int pxg  = lane & 15;
    const int ngr  = lane >> 4;
    const int px0  = pxg * 4;
    const int n0   = wv * 16 + ngr * 4;

    const int gpx = lane;
    const int gcq = wv;

    const float fi = (float)irow;
    const float fj = (float)(j0 + gpx);

    float acc2[4][4] = {};

    for (int r = 0; r < Rr; ++r) {
        float dI[Pp], dJ[Pp];
        #pragma unroll
        for (int p = 0; p < Pp; ++p) {
            float ang = (float)p * 0.78539818525314331f;
            dI[p] = (float)r * sinf(ang);
            dJ[p] = (float)r * cosf(ang);
        }

        float h[4][4] = {};

        for (int kc = 0; kc < CPk / KC; ++kc) {
            const float* w1pq = W1 + ((size_t)r * CPk + (size_t)kc * KC) * 64;
            #pragma unroll
            for (int u = 0; u < 4; ++u) {
                int f = (tid + u * 256) * 4;
                float4 v = *reinterpret_cast<const float4*>(w1pq + f);
                *reinterpret_cast<float4*>(&wbuf[f >> 6][f & 63]) = v;
            }
            const int cbase = kc * 8;
            #pragma unroll
            for (int p = 0; p < Pp; ++p) {
                float yy  = fi + dI[p];
                float xx  = fj + dJ[p];
                float y0f = floorf(yy), x0f = floorf(xx);
                float wy  = yy - y0f,   wx  = xx - x0f;
                int y0 = (int)y0f, xq = (int)x0f;
                int y1 = y0 + 1,   x1 = xq + 1;
                float m00 = (y0 >= 0 && y0 < Hh && xq >= 0 && xq < Ww) ? 1.f : 0.f;
                float m01 = (y0 >= 0 && y0 < Hh && x1 >= 0 && x1 < Ww) ? 1.f : 0.f;
                float m10 = (y1 >= 0 && y1 < Hh && xq >= 0 && xq < Ww) ? 1.f : 0.f;
                float m11 = (y1 >= 0 && y1 < Hh && x1 >= 0 && x1 < Ww) ? 1.f : 0.f;
                int y0c = y0 < 0 ? 0 : (y0 > Hh - 1 ? Hh - 1 : y0);
                int y1c = y1 < 0 ? 0 : (y1 > Hh - 1 ? Hh - 1 : y1);
                int x0c = xq < 0 ? 0 : (xq > Ww - 1 ? Ww - 1 : xq);
                int x1c = x1 < 0 ? 0 : (x1 > Ww - 1 ? Ww - 1 : x1);
                float w00 = (1.f - wy) * (1.f - wx) * m00;
                float w01 = (1.f - wy) * wx * m01;
                float w10 = wy * (1.f - wx) * m10;
                float w11 = wy * wx * m11;
                int o00 = y0c * Ww + x0c, o01 = y0c * Ww + x1c;
                int o10 = y1c * Ww + x0c, o11 = y1c * Ww + x1c;
                #pragma unroll
                for (int cc = 0; cc < 2; ++cc) {
                    int cl = gcq * 2 + cc;
                    const float* xp = x + ((size_t)b * Cc + (cbase + cl)) * HWn;
                    float val = w00 * xp[o00] + w01 * xp[o01]
                              + w10 * xp[o10] + w11 * xp[o11];
                    featT[cl * 8 + p][gpx] = val;
                }
            }
            __syncthreads();
            #pragma unroll 8
            for (int kk = 0; kk < KC; ++kk) {
                float4 av  = *reinterpret_cast<const float4*>(&featT[kk][px0]);
                float4 wv4 = *reinterpret_cast<const float4*>(&wbuf[kk][n0]);
                float aa[4] = {av.x, av.y, av.z, av.w};
                float ww[4] = {wv4.x, wv4.y, wv4.z, wv4.w};
                #pragma unroll
                for (int pi = 0; pi < 4; ++pi)
                    #pragma unroll
                    for (int qi = 0; qi < 4; ++qi)
                        h[pi][qi] = fmaf(aa[pi], ww[qi], h[pi][qi]);
            }
            __syncthreads();
        }

        #pragma unroll
        for (int pi = 0; pi < 4; ++pi) {
            #pragma unroll
            for (int qi = 0; qi < 4; ++qi)
                hbuf[px0 + pi][n0 + qi] = h[pi][qi] + b1v[r * 64 + n0 + qi];
        }
        __syncthreads();

        if (tid < PIX) {
            float s = 0.f;
            #pragma unroll
            for (int nn = 0; nn < 64; ++nn) s += hbuf[tid][nn];
            float mu = s * (1.f / 64.f);
            float s2 = 0.f;
            #pragma unroll
            for (int nn = 0; nn < 64; ++nn) {
                float d = hbuf[tid][nn] - mu;
                s2 = fmaf(d, d, s2);
            }
            mu_s[tid] = mu;
            rs_s[tid] = rsqrtf(s2 * (1.f / 64.f) + 1e-5f);
        }
        __syncthreads();

        {
            int px = tid >> 2, nbq = (tid & 3) * 16;
            float mu = mu_s[px], rs = rs_s[px];
            const float* g1p = g1v + r * 64;
            const float* btp = btv + r * 64;
            #pragma unroll
            for (int u = 0; u < 16; ++u) {
                int nn = nbq + u;
                float v = hbuf[px][nn];
                v = (v - mu) * rs * g1p[nn] + btp[nn];
                v = 0.5f * v * (1.f + erff(v * 0.70710678118654752f));
                featT[nn][px] = v;
            }
        }
        {
            const float* w2pq = W2 + (size_t)r * 64 * 64;
            #pragma unroll
            for (int u = 0; u < 4; ++u) {
                int f = (tid + u * 256) * 4;
                float4 v = *reinterpret_cast<const float4*>(w2pq + f);
                *reinterpret_cast<float4*>(&wbuf[f >> 6][f & 63]) = v;
            }
        }
        __syncthreads();

        #pragma unroll 8
        for (int kk = 0; kk < 64; ++kk) {
            float4 av  = *reinterpret_cast<const float4*>(&featT[kk][px0]);
            float4 wv4 = *reinterpret_cast<const float4*>(&wbuf[kk][n0]);
            float aa[4] = {av.x, av.y, av.z, av.w};
            float ww[4] = {wv4.x, wv4.y, wv4.z, wv4.w};
            #pragma unroll
            for (int pi = 0; pi < 4; ++pi)
                #pragma unroll
                for (int qi = 0; qi < 4; ++qi)
                    acc2[pi][qi] = fmaf(aa[pi], ww[qi], acc2[pi][qi]);
        }
        __syncthreads();
    }

    float sb2[4];
    #pragma unroll
    for (int qi = 0; qi < 4; ++qi) {
        float s = 0.f;
        for (int r = 0; r < Rr; ++r) s += b2v[r * 64 + n0 + qi];
        sb2[qi] = s;
    }
    #pragma unroll
    for (int pi = 0; pi < 4; ++pi) {
        int jj = j0 + px0 + pi;
        #pragma unroll
        for (int qi = 0; qi < 4; ++qi) {
            int n = n0 + qi;
            size_t off = ((size_t)b * Cc + n) * HWn + (size_t)irow * Ww + jj;
            float a = acc2[pi][qi] + sb2[qi];
            float wts = 1.f / (1.f + expf(-a));
            out[off] = x[off] * wts;
        }
    }
}

extern "C" void kernel_launch(void* const* d_in, const int* in_sizes, int n_in,
                              void* d_out, int out_size, void* d_ws, size_t ws_size,
                              hipStream_t stream)
{
    const float* x  = (const float*)d_in[0];
    const float* W1 = (const float*)d_in[1];
    const float* b1 = (const float*)d_in[2];
    const float* g1 = (const float*)d_in[3];
    const float* bt = (const float*)d_in[4];
    const float* W2 = (const float*)d_in[5];
    const float* b2 = (const float*)d_in[6];
    float* outp = (float*)d_out;

    if (ws_size >= 368640) {
        unsigned short* w1p = (unsigned short*)d_ws;          // 163840 bf16
        unsigned short* w2p = w1p + 163840;                    // 20480 bf16
        rrf_prepack<<<dim3(640), dim3(256), 0, stream>>>(W1, W2, w1p, w2p);
        rrf_mfma<<<dim3(1024), dim3(256), 0, stream>>>(x, w1p, w2p, b1, g1, bt, b2, outp);
    } else {
        rrf_fp32<<<dim3(1024), dim3(256), 0, stream>>>(x, W1, b1, g1, bt, W2, b2, outp);
    }
}